// Round 2
// baseline (2646.499 us; speedup 1.0000x reference)
//
#include <hip/hip_runtime.h>
#include <hip/hip_bf16.h>
#include <hip/hip_fp16.h>

#define N_NODES 50000
#define DIM 128
#define NE 800000
#define MAXD 48
#define CAP 64

typedef _Float16 half2v __attribute__((ext_vector_type(2)));

__device__ __forceinline__ float sigmf(float x){
  return __builtin_amdgcn_rcpf(1.f + __builtin_amdgcn_exp2f(-1.4426950408889634f * x));
}
__device__ __forceinline__ float tanh_fast(float x){
  float e = __builtin_amdgcn_exp2f(2.8853900817779268f * x); // e^(2x)
  return 1.f - 2.f * __builtin_amdgcn_rcpf(e + 1.f);
}
__device__ __forceinline__ unsigned short f2h(float f){
  __half h = __float2half(f);
  return *(unsigned short*)&h;
}
__device__ __forceinline__ float h2f(unsigned short u){
  __half h = *(__half*)&u;
  return __half2float(h);
}
__device__ __forceinline__ float dot2h(unsigned a, unsigned b, float c){
  union { unsigned u; half2v v; } ua, ub;
  ua.u = a; ub.u = b;
  return __builtin_amdgcn_fdot2(ua.v, ub.v, c, false);
}

__global__ void kZero(int* p, int n){
  int i = blockIdx.x*blockDim.x + threadIdx.x;
  if(i<n) p[i]=0;
}

__global__ void kColStats(const float* __restrict__ feat, float* __restrict__ P, float* __restrict__ P2){
  int d = threadIdx.x; int b = blockIdx.x;
  float s=0.f, s2=0.f;
  for(int r=b; r<N_NODES; r+=256){ float v = feat[r*DIM+d]; s+=v; s2+=v*v; }
  P[b*DIM+d]=s; P2[b*DIM+d]=s2;
}

__global__ void kFinStats(const float* __restrict__ P, const float* __restrict__ P2,
                          const float* __restrict__ gamma, const float* __restrict__ beta,
                          float* __restrict__ scale, float* __restrict__ shift){
  int d = threadIdx.x;
  float s=0.f, s2=0.f;
  for(int b=0;b<256;b++){ s+=P[b*DIM+d]; s2+=P2[b*DIM+d]; }
  float mu = s/(float)N_NODES;
  float var = s2/(float)N_NODES - mu*mu;
  float rs = rsqrtf(var + 1e-5f);
  float sc = rs*gamma[d];
  scale[d]=sc; shift[d]=beta[d]-mu*sc;
}

__global__ void kEdges(const int* __restrict__ dst, int* __restrict__ cnt, int* __restrict__ elist){
  for(int e = blockIdx.x*blockDim.x+threadIdx.x; e < NE; e += gridDim.x*blockDim.x){
    int d = dst[e];
    int slot = atomicAdd(&cnt[d],1);
    if(slot < CAP) elist[d*CAP+slot] = e;
  }
}

__global__ void kSortSrc(const int* __restrict__ src, const int* __restrict__ cnt,
                         int* __restrict__ elist, int* __restrict__ len){
  int n = blockIdx.x*blockDim.x+threadIdx.x; if(n>=N_NODES) return;
  int m = cnt[n]; if(m>CAP) m=CAP;
  int* el = elist + n*CAP;
  for(int i=1;i<m;i++){ int v=el[i]; int j=i-1; while(j>=0 && el[j]>v){ el[j+1]=el[j]; j--; } el[j+1]=v; }
  int L = m; if(L>MAXD) L=MAXD;
  len[n]=L;
  for(int t=0;t<L;t++) el[t] = src[el[t]];
}

// GI[n][0:384] = x@W_ih^T + b_ih  and  out[n][0:128] = x@W_self^T  (self term)
__global__ __launch_bounds__(256) void kXG(const float* __restrict__ feat, const float* __restrict__ scale,
    const float* __restrict__ shift, const float* __restrict__ Wih, const float* __restrict__ bih,
    const float* __restrict__ Wself, float* __restrict__ GI, float* __restrict__ out){
  __shared__ float Xs[32*129];
  __shared__ float Wt[64*128];
  int tid = threadIdx.x; int n0 = blockIdx.x*32;
  for(int idx=tid; idx<32*DIM; idx+=256){
    int nl = idx>>7, d = idx&127; int n = n0+nl;
    float v = (n<N_NODES)? feat[n*DIM+d] : 0.f;
    Xs[nl*129+d] = v*scale[d]+shift[d];
  }
  int nl = tid&31, jb = tid>>5; // jb 0..7
  for(int jt=0; jt<512; jt+=64){
    __syncthreads();
    for(int idx=tid; idx<64*DIM; idx+=256){
      int jr = idx>>7, d = idx&127; int j = jt+jr;
      Wt[idx] = (j<384)? Wih[j*DIM+d] : Wself[(j-384)*DIM+d];
    }
    __syncthreads();
    float acc[8];
    #pragma unroll
    for(int k=0;k<8;k++) acc[k]=0.f;
    for(int d=0; d<DIM; d++){
      float xv = Xs[nl*129+d];
      #pragma unroll
      for(int k=0;k<8;k++) acc[k] += xv * Wt[(jb+8*k)*DIM+d];
    }
    int n = n0+nl;
    if(n<N_NODES){
      #pragma unroll
      for(int k=0;k<8;k++){
        int j = jt + jb + 8*k;
        if(j<384) GI[(size_t)n*384+j] = acc[k] + bih[j];
        else      out[(size_t)n*DIM + (j-384)] = acc[k];
      }
    }
  }
}

// One wave per PAIR of nodes; W_hh f16-packed in LDS; h kept as f16 hi+lo (≈fp32 state).
__global__ __launch_bounds__(512,1) void kGru(const float* __restrict__ GI, const int* __restrict__ elist,
    const int* __restrict__ len, const float* __restrict__ Whh, const float* __restrict__ bhh,
    const float* __restrict__ Wneigh, float* __restrict__ out){
  __shared__ unsigned Wp[64*3*64*2];   // 96KB: [dp][kk][lane][half] f16x2 of W_hh rows j=lane+128kk+64half, dims (2dp,2dp+1)
  __shared__ unsigned Wn[64*128];      // 32KB: [dp][j] f16x2 of W_neigh
  __shared__ unsigned hsu[8][2][128];  // 8KB: per wave, per slot: [dp][0]=hi pair, [dp][1]=lo pair
  int tid = threadIdx.x;
  for(int idx=tid; idx<64*3*64*2; idx+=512){
    int half = idx&1; int r = idx>>1;
    int lane = r&63; int r2 = r>>6;
    int kk = r2%3; int dp = r2/3;
    int j = lane + 128*kk + 64*half;
    unsigned lo = f2h(Whh[j*DIM + 2*dp]);
    unsigned hi = f2h(Whh[j*DIM + 2*dp+1]);
    Wp[idx] = lo | (hi<<16);
  }
  for(int idx=tid; idx<64*128; idx+=512){
    int dp = idx>>7; int j = idx&127;
    unsigned lo = f2h(Wneigh[j*DIM+2*dp]);
    unsigned hi = f2h(Wneigh[j*DIM+2*dp+1]);
    Wn[idx] = lo | (hi<<16);
  }
  __syncthreads();
  int wid = tid>>6, lane = tid&63;
  unsigned* hA = &hsu[wid][0][0];
  unsigned* hB = &hsu[wid][1][0];
  unsigned short* hAs = (unsigned short*)hA;
  unsigned short* hBs = (unsigned short*)hB;
  float bh[6];
  #pragma unroll
  for(int k=0;k<6;k++) bh[k] = bhh[64*k + lane];
  const int npairs = (N_NODES+1)/2;
  for(int q = blockIdx.x*8 + wid; q < npairs; q += gridDim.x*8){
    int nA = 2*q, nB = 2*q+1;
    int lA = len[nA];
    int lB = (nB<N_NODES)? len[nB] : 0;
    int T = lA>lB? lA:lB;
    if(T==0) continue;
    hA[lane]=0; hA[64+lane]=0;
    hB[lane]=0; hB[64+lane]=0;
    float hA0=0.f, hA1=0.f, hB0=0.f, hB1=0.f;
    const int* eA = elist + nA*CAP;
    const int* eB = elist + nB*CAP;
    for(int t=0;t<T;t++){
      int sA = (lA>0)? eA[t<lA? t:lA-1] : 0;
      int sB = (lB>0)? eB[t<lB? t:lB-1] : 0;
      const float* gA = GI + (size_t)sA*384;
      const float* gB = GI + (size_t)sB*384;
      float giA[6], giB[6];
      #pragma unroll
      for(int k=0;k<6;k++){ giA[k]=gA[64*k+lane]; giB[k]=gB[64*k+lane]; }
      float ghA[6], ghB[6];
      #pragma unroll
      for(int k=0;k<6;k++){ ghA[k]=bh[k]; ghB[k]=bh[k]; }
      for(int dp=0; dp<64; dp++){
        uint2 ha = *(const uint2*)&hA[dp*2];   // x=hi pair, y=lo pair
        uint2 hb = *(const uint2*)&hB[dp*2];
        #pragma unroll
        for(int kk=0;kk<3;kk++){
          uint2 w = *(const uint2*)&Wp[(((dp*3)+kk)*64 + lane)*2];
          ghA[2*kk]   = dot2h(w.x, ha.x, dot2h(w.x, ha.y, ghA[2*kk]));
          ghA[2*kk+1] = dot2h(w.y, ha.x, dot2h(w.y, ha.y, ghA[2*kk+1]));
          ghB[2*kk]   = dot2h(w.x, hb.x, dot2h(w.x, hb.y, ghB[2*kk]));
          ghB[2*kk+1] = dot2h(w.y, hb.x, dot2h(w.y, hb.y, ghB[2*kk+1]));
        }
      }
      if(t<lA){
        float r0=sigmf(giA[0]+ghA[0]), r1=sigmf(giA[1]+ghA[1]);
        float z0=sigmf(giA[2]+ghA[2]), z1=sigmf(giA[3]+ghA[3]);
        float n0=tanh_fast(giA[4]+r0*ghA[4]), n1=tanh_fast(giA[5]+r1*ghA[5]);
        hA0 = (1.f-z0)*n0 + z0*hA0;
        hA1 = (1.f-z1)*n1 + z1*hA1;
        unsigned short u0 = f2h(hA0); unsigned short l0 = f2h(hA0 - h2f(u0));
        unsigned short u1 = f2h(hA1); unsigned short l1 = f2h(hA1 - h2f(u1));
        int dp0 = lane>>1, o0 = lane&1, dp1 = (64+lane)>>1, o1 = lane&1;
        hAs[dp0*4+o0] = u0; hAs[dp0*4+2+o0] = l0;
        hAs[dp1*4+o1] = u1; hAs[dp1*4+2+o1] = l1;
      }
      if(t<lB){
        float r0=sigmf(giB[0]+ghB[0]), r1=sigmf(giB[1]+ghB[1]);
        float z0=sigmf(giB[2]+ghB[2]), z1=sigmf(giB[3]+ghB[3]);
        float n0=tanh_fast(giB[4]+r0*ghB[4]), n1=tanh_fast(giB[5]+r1*ghB[5]);
        hB0 = (1.f-z0)*n0 + z0*hB0;
        hB1 = (1.f-z1)*n1 + z1*hB1;
        unsigned short u0 = f2h(hB0); unsigned short l0 = f2h(hB0 - h2f(u0));
        unsigned short u1 = f2h(hB1); unsigned short l1 = f2h(hB1 - h2f(u1));
        int dp0 = lane>>1, o0 = lane&1, dp1 = (64+lane)>>1, o1 = lane&1;
        hBs[dp0*4+o0] = u0; hBs[dp0*4+2+o0] = l0;
        hBs[dp1*4+o1] = u1; hBs[dp1*4+2+o1] = l1;
      }
    }
    if(lA>0){
      float o0=0.f,o1=0.f;
      for(int dp=0;dp<64;dp++){
        uint2 ha = *(const uint2*)&hA[dp*2];
        o0 = dot2h(Wn[dp*128+lane],    ha.x, dot2h(Wn[dp*128+lane],    ha.y, o0));
        o1 = dot2h(Wn[dp*128+64+lane], ha.x, dot2h(Wn[dp*128+64+lane], ha.y, o1));
      }
      out[(size_t)nA*DIM+lane]    += o0;
      out[(size_t)nA*DIM+64+lane] += o1;
    }
    if(lB>0){
      float o0=0.f,o1=0.f;
      for(int dp=0;dp<64;dp++){
        uint2 hb = *(const uint2*)&hB[dp*2];
        o0 = dot2h(Wn[dp*128+lane],    hb.x, dot2h(Wn[dp*128+lane],    hb.y, o0));
        o1 = dot2h(Wn[dp*128+64+lane], hb.x, dot2h(Wn[dp*128+64+lane], hb.y, o1));
      }
      out[(size_t)nB*DIM+lane]    += o0;
      out[(size_t)nB*DIM+64+lane] += o1;
    }
  }
}

extern "C" void kernel_launch(void* const* d_in, const int* in_sizes, int n_in,
                              void* d_out, int out_size, void* d_ws, size_t ws_size,
                              hipStream_t stream){
  const float* feat  = (const float*)d_in[0];
  const int*   src   = (const int*)d_in[1];
  const int*   dst   = (const int*)d_in[2];
  const float* gamma = (const float*)d_in[3];
  const float* beta  = (const float*)d_in[4];
  const float* Wih   = (const float*)d_in[5];
  const float* Whh   = (const float*)d_in[6];
  const float* bih   = (const float*)d_in[7];
  const float* bhh   = (const float*)d_in[8];
  const float* Wself = (const float*)d_in[9];
  const float* Wneigh= (const float*)d_in[10];
  float* out = (float*)d_out;

  char* ws = (char*)d_ws;
  size_t off = 0;
  auto alloc = [&](size_t bytes)->void*{ void* p = ws+off; off += (bytes+511)&~(size_t)511; return p; };
  float* P     = (float*)alloc(256*128*4);
  float* P2    = (float*)alloc(256*128*4);
  float* scale = (float*)alloc(512);
  float* shift = (float*)alloc(512);
  int*   cnt   = (int*)alloc((size_t)N_NODES*4);
  int*   lenp  = (int*)alloc((size_t)N_NODES*4);
  int*   elist = (int*)alloc((size_t)N_NODES*CAP*4);
  float* GI    = (float*)alloc((size_t)N_NODES*384*4);

  kZero<<<(N_NODES+255)/256, 256, 0, stream>>>(cnt, N_NODES);
  kColStats<<<256,128,0,stream>>>(feat, P, P2);
  kFinStats<<<1,128,0,stream>>>(P,P2,gamma,beta,scale,shift);
  kEdges<<<1024,256,0,stream>>>(dst, cnt, elist);
  kSortSrc<<<(N_NODES+255)/256,256,0,stream>>>(src, cnt, elist, lenp);
  kXG<<<(N_NODES+31)/32,256,0,stream>>>(feat, scale, shift, Wih, bih, Wself, GI, out);
  kGru<<<1024,512,0,stream>>>(GI, elist, lenp, Whh, bhh, Wneigh, out);
}

// Round 3
// 886.668 us; speedup vs baseline: 2.9848x; 2.9848x over previous
//
#include <hip/hip_runtime.h>
#include <hip/hip_fp16.h>

#define N_NODES 50000
#define DIM 128
#define NE 800000
#define MAXD 48
#define CAP 64
#define NGRP (N_NODES/16)

typedef _Float16 f16x8 __attribute__((ext_vector_type(8)));
typedef float f32x4 __attribute__((ext_vector_type(4)));

__device__ __forceinline__ float sigmf(float x){
  return __builtin_amdgcn_rcpf(1.f + __builtin_amdgcn_exp2f(-1.4426950408889634f * x));
}
__device__ __forceinline__ float tanh_fast(float x){
  float e = __builtin_amdgcn_exp2f(2.8853900817779268f * x); // e^(2x)
  return 1.f - 2.f * __builtin_amdgcn_rcpf(e + 1.f);
}
__device__ __forceinline__ unsigned short f2h(float f){
  union{_Float16 h; unsigned short s;} c; c.h=(_Float16)f; return c.s;
}
__device__ __forceinline__ float h2f(unsigned short u){
  union{unsigned short s; _Float16 h;} c; c.s=u; return (float)c.h;
}

__global__ void kZero(int* p, int n){
  int i = blockIdx.x*blockDim.x + threadIdx.x;
  if(i<n) p[i]=0;
}

__global__ void kColStats(const float* __restrict__ feat, float* __restrict__ P, float* __restrict__ P2){
  int d = threadIdx.x; int b = blockIdx.x;
  float s=0.f, s2=0.f;
  for(int r=b; r<N_NODES; r+=256){ float v = feat[r*DIM+d]; s+=v; s2+=v*v; }
  P[b*DIM+d]=s; P2[b*DIM+d]=s2;
}

__global__ void kFinStats(const float* __restrict__ P, const float* __restrict__ P2,
                          const float* __restrict__ gamma, const float* __restrict__ beta,
                          float* __restrict__ scale, float* __restrict__ shift){
  int d = threadIdx.x;
  float s=0.f, s2=0.f;
  for(int b=0;b<256;b++){ s+=P[b*DIM+d]; s2+=P2[b*DIM+d]; }
  float mu = s/(float)N_NODES;
  float var = s2/(float)N_NODES - mu*mu;
  float rs = rsqrtf(var + 1e-5f);
  float sc = rs*gamma[d];
  scale[d]=sc; shift[d]=beta[d]-mu*sc;
}

__global__ void kEdges(const int* __restrict__ dst, int* __restrict__ cnt, int* __restrict__ elist){
  for(int e = blockIdx.x*blockDim.x+threadIdx.x; e < NE; e += gridDim.x*blockDim.x){
    int d = dst[e];
    int slot = atomicAdd(&cnt[d],1);
    if(slot < CAP) elist[d*CAP+slot] = e;
  }
}

__global__ void kSortSrc(const int* __restrict__ src, const int* __restrict__ cnt,
                         int* __restrict__ elist, int* __restrict__ len){
  int n = blockIdx.x*blockDim.x+threadIdx.x; if(n>=N_NODES) return;
  int m = cnt[n]; if(m>CAP) m=CAP;
  int* el = elist + n*CAP;
  for(int i=1;i<m;i++){ int v=el[i]; int j=i-1; while(j>=0 && el[j]>v){ el[j+1]=el[j]; j--; } el[j+1]=v; }
  int L = m; if(L>MAXD) L=MAXD;
  len[n]=L;
  for(int t=0;t<L;t++) el[t] = src[el[t]];
}

__global__ void kHist(const int* __restrict__ len, int* __restrict__ hist){
  int n=blockIdx.x*blockDim.x+threadIdx.x;
  if(n<N_NODES) atomicAdd(&hist[len[n]],1);
}
__global__ void kScan(const int* __restrict__ hist, int* __restrict__ offs){
  if(threadIdx.x==0){ int s=0; for(int i=0;i<=MAXD;i++){ offs[i]=s; s+=hist[i]; } }
}
__global__ void kScatter(const int* __restrict__ len, int* __restrict__ offs, int* __restrict__ perm){
  int n=blockIdx.x*blockDim.x+threadIdx.x;
  if(n<N_NODES){ int r=atomicAdd((int*)&offs[len[n]],1); perm[r]=n; }
}

// GIh[n][0:384] = f16(x@W_ih^T + b_ih), out[n][0:128] = x@W_self^T (fp32 self term)
__global__ __launch_bounds__(256) void kXG(const float* __restrict__ feat, const float* __restrict__ scale,
    const float* __restrict__ shift, const float* __restrict__ Wih, const float* __restrict__ bih,
    const float* __restrict__ Wself, unsigned short* __restrict__ GIh, float* __restrict__ out){
  __shared__ float Xs[32*129];
  __shared__ float Wt[64*128];
  int tid = threadIdx.x; int n0 = blockIdx.x*32;
  for(int idx=tid; idx<32*DIM; idx+=256){
    int nl = idx>>7, d = idx&127; int n = n0+nl;
    float v = (n<N_NODES)? feat[n*DIM+d] : 0.f;
    Xs[nl*129+d] = v*scale[d]+shift[d];
  }
  int nl = tid&31, jb = tid>>5; // jb 0..7
  for(int jt=0; jt<512; jt+=64){
    __syncthreads();
    for(int idx=tid; idx<64*DIM; idx+=256){
      int jr = idx>>7, d = idx&127; int j = jt+jr;
      Wt[idx] = (j<384)? Wih[j*DIM+d] : Wself[(j-384)*DIM+d];
    }
    __syncthreads();
    float acc[8];
    #pragma unroll
    for(int k=0;k<8;k++) acc[k]=0.f;
    for(int d=0; d<DIM; d++){
      float xv = Xs[nl*129+d];
      #pragma unroll
      for(int k=0;k<8;k++) acc[k] += xv * Wt[(jb+8*k)*DIM+d];
    }
    int n = n0+nl;
    if(n<N_NODES){
      #pragma unroll
      for(int k=0;k<8;k++){
        int j = jt + jb + 8*k;
        if(j<384) GIh[(size_t)n*384+j] = f2h(acc[k] + bih[j]);
        else      out[(size_t)n*DIM + (j-384)] = acc[k];
      }
    }
  }
}

// MFMA-batched GRU: one 4-wave block per group of 16 degree-sorted nodes.
// Wave w owns d-slice [32w,32w+32) of all 3 gates. W_hh A-frags in registers,
// h as hi/lo f16 planes in swizzled double-buffered LDS.
__global__ __launch_bounds__(256,2) void kGruM(const unsigned short* __restrict__ GIh,
    const int* __restrict__ elist, const int* __restrict__ len, const int* __restrict__ perm,
    const float* __restrict__ Whh, const float* __restrict__ bhh,
    const float* __restrict__ Wneigh, float* __restrict__ out)
{
  __shared__ unsigned short hbuf[2][2][16][128]; // [buf][plane hi/lo][g][d], XOR-swizzled rows, 16KB
  __shared__ unsigned short WnL[128*128];        // W_neigh f16 linear [j][d], 32KB
  const int tid=threadIdx.x, w=tid>>6, l=tid&63, g=l&15, q=l>>4;

  for(int i=tid;i<2048;i+=256){
    const float* p=&Wneigh[i*8];
    unsigned u0=(unsigned)f2h(p[0])|((unsigned)f2h(p[1])<<16);
    unsigned u1=(unsigned)f2h(p[2])|((unsigned)f2h(p[3])<<16);
    unsigned u2=(unsigned)f2h(p[4])|((unsigned)f2h(p[5])<<16);
    unsigned u3=(unsigned)f2h(p[6])|((unsigned)f2h(p[7])<<16);
    ((uint4*)WnL)[i]=make_uint4(u0,u1,u2,u3);
  }
  // W_hh A-fragments: A[m][k]: m=l&15 (j-row), k=8*(l>>4)+e (d)
  f16x8 Wf[6][4];
  #pragma unroll
  for(int fi=0;fi<6;fi++){
    const int gt=fi>>1, tt=fi&1;
    const int j=gt*128+32*w+16*tt+g;
    #pragma unroll
    for(int ks=0;ks<4;ks++){
      const float* p=&Whh[j*DIM+32*ks+8*q];
      f16x8 v;
      #pragma unroll
      for(int e=0;e<8;e++) v[e]=(_Float16)p[e];
      Wf[fi][ks]=v;
    }
  }
  float bh[6][4];
  #pragma unroll
  for(int fi=0;fi<6;fi++){ const int gt=fi>>1, tt=fi&1;
    #pragma unroll
    for(int r=0;r<4;r++) bh[fi][r]=bhh[gt*128+32*w+16*tt+4*q+r];
  }

  for(int grp=blockIdx.x; grp<NGRP; grp+=gridDim.x){
    __syncthreads();                       // prev epilogue readers done
    for(int i=tid;i<1024;i+=256) ((uint4*)hbuf)[i]=make_uint4(0,0,0,0);
    const int n_g=perm[grp*16+g];
    const int Lg=len[n_g];
    int T=Lg;
    T=max(T,__shfl_xor(T,1)); T=max(T,__shfl_xor(T,2));
    T=max(T,__shfl_xor(T,4)); T=max(T,__shfl_xor(T,8));
    __syncthreads();
    const int* el=elist+(size_t)n_g*CAP;
    int sNext=0; uint2 gi[6];
    if(T>0){
      int s0=(Lg>0)?el[0]:0;
      sNext=(Lg>1)?el[1]:s0;
      const unsigned short* gp=GIh+(size_t)s0*384;
      #pragma unroll
      for(int fi=0;fi<6;fi++){ const int gt=fi>>1, tt=fi&1;
        gi[fi]=*(const uint2*)&gp[gt*128+32*w+16*tt+4*q]; }
    }
    float h[2][4]={{0.f,0.f,0.f,0.f},{0.f,0.f,0.f,0.f}};
    for(int t=0;t<T;t++){
      const int cb=t&1, cbn=cb^1;
      // B-frags: B[k][n]: n=l&15 (node g), k=8*(l>>4)+e (d); swizzled block read
      f16x8 Bf[4][2];
      #pragma unroll
      for(int ks=0;ks<4;ks++){
        #pragma unroll
        for(int p=0;p<2;p++){
          const char* bp=(const char*)hbuf + ((cb*2+p)*16+g)*256 + (((4*ks+q)^(g&7))*16);
          Bf[ks][p]=*(const f16x8*)bp;
        }
      }
      f32x4 acc[6];
      #pragma unroll
      for(int fi=0;fi<6;fi++){
        f32x4 a={0.f,0.f,0.f,0.f};
        #pragma unroll
        for(int ks=0;ks<4;ks++) a=__builtin_amdgcn_mfma_f32_16x16x32_f16(Wf[fi][ks],Bf[ks][1],a,0,0,0);
        #pragma unroll
        for(int ks=0;ks<4;ks++) a=__builtin_amdgcn_mfma_f32_16x16x32_f16(Wf[fi][ks],Bf[ks][0],a,0,0,0);
        acc[fi]=a;
      }
      float giv[6][4];
      #pragma unroll
      for(int fi=0;fi<6;fi++){
        giv[fi][0]=h2f((unsigned short)(gi[fi].x&0xffffu));
        giv[fi][1]=h2f((unsigned short)(gi[fi].x>>16));
        giv[fi][2]=h2f((unsigned short)(gi[fi].y&0xffffu));
        giv[fi][3]=h2f((unsigned short)(gi[fi].y>>16));
      }
      if(t+1<T){
        const unsigned short* gp=GIh+(size_t)sNext*384;
        #pragma unroll
        for(int fi=0;fi<6;fi++){ const int gt=fi>>1, tt=fi&1;
          gi[fi]=*(const uint2*)&gp[gt*128+32*w+16*tt+4*q]; }
      }
      int ii=t+2; ii=(ii>Lg-1)?(Lg-1):ii; ii=(ii<0)?0:ii;
      const int sN2=(Lg>0)?el[ii]:0;
      const bool act=(t<Lg);
      #pragma unroll
      for(int tt=0;tt<2;tt++){
        #pragma unroll
        for(int r=0;r<4;r++){
          float rr=sigmf(giv[tt][r]+acc[tt][r]+bh[tt][r]);
          float zz=sigmf(giv[2+tt][r]+acc[2+tt][r]+bh[2+tt][r]);
          float nn=tanh_fast(giv[4+tt][r]+rr*(acc[4+tt][r]+bh[4+tt][r]));
          float hn=(1.f-zz)*nn+zz*h[tt][r];
          h[tt][r]=act?hn:h[tt][r];
        }
      }
      #pragma unroll
      for(int tt=0;tt<2;tt++){
        unsigned short a0=f2h(h[tt][0]),a1=f2h(h[tt][1]),a2=f2h(h[tt][2]),a3=f2h(h[tt][3]);
        unsigned short b0=f2h(h[tt][0]-h2f(a0)),b1=f2h(h[tt][1]-h2f(a1));
        unsigned short b2=f2h(h[tt][2]-h2f(a2)),b3=f2h(h[tt][3]-h2f(a3));
        const int blk=((4*w+2*tt+(q>>1))^(g&7));
        const int sub=8*(q&1);
        char* p0=(char*)hbuf + ((cbn*2+0)*16+g)*256 + blk*16 + sub;
        char* p1=(char*)hbuf + ((cbn*2+1)*16+g)*256 + blk*16 + sub;
        *(uint2*)p0=make_uint2((unsigned)a0|((unsigned)a1<<16),(unsigned)a2|((unsigned)a3<<16));
        *(uint2*)p1=make_uint2((unsigned)b0|((unsigned)b1<<16),(unsigned)b2|((unsigned)b3<<16));
      }
      __syncthreads();
      sNext=sN2;
    }
    // epilogue: out += W_neigh · h_final (hi+lo planes)
    const int fb=T&1;
    #pragma unroll
    for(int tt=0;tt<2;tt++){
      f32x4 a={0.f,0.f,0.f,0.f};
      #pragma unroll
      for(int ks=0;ks<4;ks++){
        const f16x8 Af=*(const f16x8*)&WnL[(32*w+16*tt+g)*DIM + 32*ks+8*q];
        const char* bl=(const char*)hbuf + ((fb*2+1)*16+g)*256 + (((4*ks+q)^(g&7))*16);
        const char* bhp=(const char*)hbuf + ((fb*2+0)*16+g)*256 + (((4*ks+q)^(g&7))*16);
        a=__builtin_amdgcn_mfma_f32_16x16x32_f16(Af,*(const f16x8*)bl,a,0,0,0);
        a=__builtin_amdgcn_mfma_f32_16x16x32_f16(Af,*(const f16x8*)bhp,a,0,0,0);
      }
      float* po=&out[(size_t)n_g*DIM + 32*w+16*tt+4*q];
      float4 cur=*(float4*)po;
      cur.x+=a[0]; cur.y+=a[1]; cur.z+=a[2]; cur.w+=a[3];
      *(float4*)po=cur;
    }
  }
}

extern "C" void kernel_launch(void* const* d_in, const int* in_sizes, int n_in,
                              void* d_out, int out_size, void* d_ws, size_t ws_size,
                              hipStream_t stream){
  const float* feat  = (const float*)d_in[0];
  const int*   src   = (const int*)d_in[1];
  const int*   dst   = (const int*)d_in[2];
  const float* gamma = (const float*)d_in[3];
  const float* beta  = (const float*)d_in[4];
  const float* Wih   = (const float*)d_in[5];
  const float* Whh   = (const float*)d_in[6];
  const float* bih   = (const float*)d_in[7];
  const float* bhh   = (const float*)d_in[8];
  const float* Wself = (const float*)d_in[9];
  const float* Wneigh= (const float*)d_in[10];
  float* out = (float*)d_out;

  char* ws = (char*)d_ws;
  size_t off = 0;
  auto alloc = [&](size_t bytes)->void*{ void* p = ws+off; off += (bytes+511)&~(size_t)511; return p; };
  float* P     = (float*)alloc(256*128*4);
  float* P2    = (float*)alloc(256*128*4);
  float* scale = (float*)alloc(512);
  float* shift = (float*)alloc(512);
  int*   cnt   = (int*)alloc((size_t)N_NODES*4);
  int*   lenp  = (int*)alloc((size_t)N_NODES*4);
  int*   hist  = (int*)alloc((MAXD+1)*4);
  int*   offs  = (int*)alloc((MAXD+1)*4);
  int*   perm  = (int*)alloc((size_t)N_NODES*4);
  int*   elist = (int*)alloc((size_t)N_NODES*CAP*4);
  unsigned short* GIh = (unsigned short*)alloc((size_t)N_NODES*384*2);

  kZero<<<(N_NODES+255)/256, 256, 0, stream>>>(cnt, N_NODES);
  kZero<<<1, 64, 0, stream>>>(hist, MAXD+1);
  kColStats<<<256,128,0,stream>>>(feat, P, P2);
  kFinStats<<<1,128,0,stream>>>(P,P2,gamma,beta,scale,shift);
  kEdges<<<1024,256,0,stream>>>(dst, cnt, elist);
  kSortSrc<<<(N_NODES+255)/256,256,0,stream>>>(src, cnt, elist, lenp);
  kHist<<<(N_NODES+255)/256,256,0,stream>>>(lenp, hist);
  kScan<<<1,64,0,stream>>>(hist, offs);
  kScatter<<<(N_NODES+255)/256,256,0,stream>>>(lenp, offs, perm);
  kXG<<<(N_NODES+31)/32,256,0,stream>>>(feat, scale, shift, Wih, bih, Wself, GIh, out);
  kGruM<<<512,256,0,stream>>>(GIh, elist, lenp, perm, Whh, bhh, Wneigh, out);
}